// Round 2
// baseline (719.590 us; speedup 1.0000x reference)
//
#include <hip/hip_runtime.h>
#include <hip/hip_bf16.h>

#define NN 100000
#define NE 800000
// D=128, H=4, C=32

typedef __attribute__((ext_vector_type(8))) short bf16x8;
typedef __attribute__((ext_vector_type(4))) float f32x4;
typedef unsigned short ushort_t;

static __device__ __forceinline__ short f2bf(float f) {
    union { float f; unsigned u; } v; v.f = f;
    unsigned u = v.u;
    unsigned r = u + 0x7FFFu + ((u >> 16) & 1u);   // RNE
    return (short)(r >> 16);
}
static __device__ __forceinline__ float bf2f(unsigned short u) {
    union { unsigned u; float f; } v; v.u = ((unsigned)u) << 16;
    return v.f;
}

// ---------------- weight prep: W[k][c] fp32 -> Wt[c][k] bf16, 9 matrices ------------
__global__ void prep_w_k(const float* __restrict__ w_in, const float* __restrict__ Wl,
                         const float* __restrict__ Wr, const float* __restrict__ Wres,
                         ushort_t* __restrict__ wt)
{
    __shared__ float tile[32][33];
    int m = blockIdx.z;
    const float* src;
    if (m == 0)      src = w_in;
    else if (m < 4)  src = Wl + (size_t)(m - 1) * 16384;
    else if (m < 7)  src = Wr + (size_t)(m - 4) * 16384;
    else             src = Wres + (size_t)(m - 7) * 16384;
    ushort_t* dst = wt + (size_t)m * 16384;

    int tx = threadIdx.x, ty = threadIdx.y;
    int k0 = blockIdx.x * 32, c0 = blockIdx.y * 32;
    #pragma unroll
    for (int j = 0; j < 4; ++j)
        tile[ty + 8 * j][tx] = src[(size_t)(k0 + ty + 8 * j) * 128 + c0 + tx];
    __syncthreads();
    #pragma unroll
    for (int j = 0; j < 4; ++j)
        dst[(size_t)(c0 + ty + 8 * j) * 128 + k0 + tx] = (ushort_t)f2bf(tile[tx][ty + 8 * j]);
}

// ---------------- P prep: P[i] = [Wl*at6 | Wr*at6] (128x8, stored [col][k] bf16),
//                  q[i][h] = bl . at6 (heads), q[i][4..7]=0 ------------------------
// logit = 0.6*at.xl[src] + 0.6*at.xr[dst] + sum_c 0.4*at[c]*|xl+xr|
// (leaky(s) = 0.6 s + 0.4 |s|); linear terms become h @ P + q, computed in gemm_k.
__global__ void prep_p_k(const float* __restrict__ Wl, const float* __restrict__ Wr,
                         const float* __restrict__ att, const float* __restrict__ bl,
                         ushort_t* __restrict__ Pmat, float* __restrict__ qvec)
{
    int i = blockIdx.x;          // layer
    int k = threadIdx.x;         // 0..127
    __shared__ float at6[128];
    __shared__ float qb[128];
    at6[k] = 0.6f * att[i * 128 + k];
    qb[k]  = bl[i * 128 + k];
    __syncthreads();
    const float* wl = Wl + (size_t)i * 16384 + (size_t)k * 128;
    const float* wr = Wr + (size_t)i * 16384 + (size_t)k * 128;
    float pl[4] = {0.f,0.f,0.f,0.f}, pr[4] = {0.f,0.f,0.f,0.f};
    for (int c = 0; c < 128; ++c) {
        int h = c >> 5;
        pl[h] = fmaf(wl[c], at6[c], pl[h]);
        pr[h] = fmaf(wr[c], at6[c], pr[h]);
    }
    ushort_t* P = Pmat + (size_t)i * 2048;       // [16 cols][128 k]
    #pragma unroll
    for (int h = 0; h < 4; ++h) {
        P[(size_t)h * 128 + k]       = (ushort_t)f2bf(pl[h]);
        P[(size_t)(4 + h) * 128 + k] = (ushort_t)f2bf(pr[h]);
    }
    #pragma unroll
    for (int h = 8; h < 16; ++h) P[(size_t)h * 128 + k] = 0;
    __syncthreads();
    if (k < 4) {
        float s = 0.f;
        for (int c = 0; c < 32; ++c) s += qb[k * 32 + c] * at6[k * 32 + c];
        qvec[i * 8 + k] = s;
        qvec[i * 8 + 4 + k] = 0.f;
    }
}

// ---------------- GEMM: 128-row tiles, B-tile staged dense in LDS ----------------
// out = A[M x 128] @ wt[w_y]^T + bias.  y==0 additionally computes
// dlr6[N x 8] = A @ P + q via 8 extra MFMAs (A fragments already in registers).
template<int A_FP32>
__global__ __launch_bounds__(256, 4)
void gemm_k(const void* __restrict__ Av, const ushort_t* __restrict__ wt,
            int w0, int w1, int w2,
            const float* __restrict__ bias0, const float* __restrict__ bias2,
            ushort_t* __restrict__ out0, int Dout0, ushort_t* __restrict__ out2, int M,
            const ushort_t* __restrict__ Pmat, const float* __restrict__ qvec,
            float* __restrict__ dlr6)
{
    __shared__ short Bs[128][136];   // B-tile [col][k]; reused as C-tile [row][col]
    __shared__ short Ps[16][136];    // P-tile [col][k]
    const int tid = threadIdx.x;
    const int rowBlk = blockIdx.x * 128;
    const int y = blockIdx.y;
    const ushort_t* W = wt + (size_t)((y == 0) ? w0 : (y == 1) ? w1 : w2) * 16384;
    const float* bias = (y == 0) ? bias0 : ((y == 2) ? bias2 : nullptr);
    ushort_t* out = (y == 2) ? out2 : out0;
    const int Dout   = (y == 2) ? 128 : Dout0;
    const int colOff = (y == 1) ? 128 : 0;
    const bool doP = (y == 0) && (Pmat != nullptr);

    const int wave = tid >> 6;
    const int lane = tid & 63;
    const int quad = lane >> 4;
    const int lr   = lane & 15;

    const int row0 = rowBlk + wave * 32 + lr;       // A fragment rows
    const int row1 = row0 + 16;

    // ---- A fragments direct from global (issued first, latency-hidden) ----
    bf16x8 afr[4][2];
    #pragma unroll
    for (int ks = 0; ks < 4; ++ks) {
        int kb = ks * 32 + quad * 8;
        bf16x8 a0 = (bf16x8)0, a1 = (bf16x8)0;
        if (A_FP32) {
            const float* A = (const float*)Av;
            if (row0 < M) {
                float4 v0 = *(const float4*)(A + (size_t)row0 * 128 + kb);
                float4 v1 = *(const float4*)(A + (size_t)row0 * 128 + kb + 4);
                a0[0]=f2bf(v0.x); a0[1]=f2bf(v0.y); a0[2]=f2bf(v0.z); a0[3]=f2bf(v0.w);
                a0[4]=f2bf(v1.x); a0[5]=f2bf(v1.y); a0[6]=f2bf(v1.z); a0[7]=f2bf(v1.w);
            }
            if (row1 < M) {
                float4 v0 = *(const float4*)(A + (size_t)row1 * 128 + kb);
                float4 v1 = *(const float4*)(A + (size_t)row1 * 128 + kb + 4);
                a1[0]=f2bf(v0.x); a1[1]=f2bf(v0.y); a1[2]=f2bf(v0.z); a1[3]=f2bf(v0.w);
                a1[4]=f2bf(v1.x); a1[5]=f2bf(v1.y); a1[6]=f2bf(v1.z); a1[7]=f2bf(v1.w);
            }
        } else {
            const ushort_t* A = (const ushort_t*)Av;
            if (row0 < M) a0 = *(const bf16x8*)(A + (size_t)row0 * 128 + kb);
            if (row1 < M) a1 = *(const bf16x8*)(A + (size_t)row1 * 128 + kb);
        }
        afr[ks][0] = a0; afr[ks][1] = a1;
    }

    // ---- stage B-tile densely; stage P-tile if needed ----
    #pragma unroll
    for (int i = 0; i < 8; ++i) {
        int linear = tid + 256 * i;              // 2048 16B chunks
        int r  = linear >> 4;
        int c8 = (linear & 15) << 3;
        *(bf16x8*)&Bs[r][c8] = *(const bf16x8*)(W + (size_t)r * 128 + c8);
    }
    if (doP) {
        int r  = tid >> 4;                       // 0..15
        int c8 = (tid & 15) << 3;
        *(bf16x8*)&Ps[r][c8] = *(const bf16x8*)(Pmat + (size_t)r * 128 + c8);
    }
    __syncthreads();

    f32x4 acc[2][8];
    #pragma unroll
    for (int mt = 0; mt < 2; ++mt)
        #pragma unroll
        for (int nt = 0; nt < 8; ++nt) acc[mt][nt] = (f32x4)(0.0f);
    f32x4 accP[2];
    accP[0] = (f32x4)(0.0f); accP[1] = (f32x4)(0.0f);

    #pragma unroll
    for (int ks = 0; ks < 4; ++ks) {
        int kb = ks * 32 + quad * 8;
        #pragma unroll
        for (int nt = 0; nt < 8; ++nt) {
            bf16x8 b = *(const bf16x8*)&Bs[nt * 16 + lr][kb];
            acc[0][nt] = __builtin_amdgcn_mfma_f32_16x16x32_bf16(afr[ks][0], b, acc[0][nt], 0, 0, 0);
            acc[1][nt] = __builtin_amdgcn_mfma_f32_16x16x32_bf16(afr[ks][1], b, acc[1][nt], 0, 0, 0);
        }
        if (doP) {
            bf16x8 pb = *(const bf16x8*)&Ps[lr][kb];
            accP[0] = __builtin_amdgcn_mfma_f32_16x16x32_bf16(afr[ks][0], pb, accP[0], 0, 0, 0);
            accP[1] = __builtin_amdgcn_mfma_f32_16x16x32_bf16(afr[ks][1], pb, accP[1], 0, 0, 0);
        }
    }

    // ---- dlr6 epilogue (cols 0..7 of the P-tile): row-scattered f32 stores ----
    if (doP && lr < 8) {
        float qv = qvec[lr];
        #pragma unroll
        for (int mt = 0; mt < 2; ++mt)
            #pragma unroll
            for (int r = 0; r < 4; ++r) {
                int row = rowBlk + wave * 32 + mt * 16 + quad * 4 + r;
                if (row < M) dlr6[(size_t)row * 8 + lr] = accP[mt][r] + qv;
            }
    }

    // ---- epilogue: reuse Bs as C-tile; C/D layout col = lane&15, row = quad*4 + reg
    __syncthreads();                             // all waves done reading B
    #pragma unroll
    for (int mt = 0; mt < 2; ++mt)
        #pragma unroll
        for (int nt = 0; nt < 8; ++nt) {
            int col = nt * 16 + lr;
            float b = bias ? bias[col] : 0.0f;
            #pragma unroll
            for (int r = 0; r < 4; ++r) {
                int row = wave * 32 + mt * 16 + quad * 4 + r;
                Bs[row][col] = f2bf(acc[mt][nt][r] + b);
            }
        }
    __syncthreads();
    #pragma unroll
    for (int i = 0; i < 8; ++i) {
        int linear = tid + 256 * i;              // 2048 16B chunks
        int r  = linear >> 4;
        int c8 = (linear & 15) << 3;
        int gr = rowBlk + r;
        if (gr < M)
            *(bf16x8*)(out + (size_t)gr * Dout + colOff + c8) = *(const bf16x8*)&Bs[r][c8];
    }
}

// ---------------- CSR build ----------------
__global__ void count_k(const int* __restrict__ dst, int* __restrict__ deg) {
    int e = blockIdx.x * 256 + threadIdx.x;
    if (e < NE) atomicAdd(&deg[dst[e]], 1);
}

__global__ void scan1_k(const int* __restrict__ deg, int* __restrict__ excl,
                        int* __restrict__ bsum) {
    __shared__ int buf[256];
    int i = blockIdx.x * 256 + threadIdx.x;
    int v = (i < NN) ? deg[i] : 0;
    buf[threadIdx.x] = v; __syncthreads();
    for (int off = 1; off < 256; off <<= 1) {
        int t = (threadIdx.x >= off) ? buf[threadIdx.x - off] : 0;
        __syncthreads();
        buf[threadIdx.x] += t;
        __syncthreads();
    }
    if (i < NN) excl[i] = buf[threadIdx.x] - v;
    if (threadIdx.x == 255) bsum[blockIdx.x] = buf[255];
}

__global__ void scan2_k(int* __restrict__ bsum, int nb, int* __restrict__ total) {
    __shared__ int buf[512];
    int v = (threadIdx.x < nb) ? bsum[threadIdx.x] : 0;
    buf[threadIdx.x] = v; __syncthreads();
    for (int off = 1; off < 512; off <<= 1) {
        int t = (threadIdx.x >= off) ? buf[threadIdx.x - off] : 0;
        __syncthreads();
        buf[threadIdx.x] += t;
        __syncthreads();
    }
    if (threadIdx.x < nb) bsum[threadIdx.x] = buf[threadIdx.x] - v;  // exclusive base
    if (threadIdx.x == 511) *total = buf[511];
}

__global__ void scan3_k(int* __restrict__ row_ptr, const int* __restrict__ bsum,
                        int* __restrict__ cursor) {
    int i = blockIdx.x * 256 + threadIdx.x;
    if (i < NN) {
        int v = row_ptr[i] + bsum[blockIdx.x];
        row_ptr[i] = v;
        cursor[i]  = v;
    }
}

__global__ void scatter_k(const int* __restrict__ src, const int* __restrict__ dst,
                          int* __restrict__ cursor, int* __restrict__ csr_src) {
    int e = blockIdx.x * 256 + threadIdx.x;
    if (e < NE) {
        int p = atomicAdd(&cursor[dst[e]], 1);
        csr_src[p] = src[e];
    }
}

// ---------------- GATv2 aggregate: one wave per destination node, 4 edges/iter --------
// Edge loop only computes the nonlinear part of the logit (sum at4*|xl+xr|);
// linear parts come precomputed in dlr6 (from gemm_k's P-MFMA path).
// Granularity 8->4: Poisson(8) degrees waste ~30% of slots at 8, ~12% at 4.
__global__ __launch_bounds__(256, 8)
void gat_aggregate_k(const ushort_t* __restrict__ xlr, const float* __restrict__ dlr6,
                     const int* __restrict__ row_ptr, const int* __restrict__ csr_src,
                     const float* __restrict__ att, const float* __restrict__ b_out,
                     ushort_t* __restrict__ g)
{
    int node = blockIdx.x * 4 + (threadIdx.x >> 6);
    int lane = threadIdx.x & 63;
    int slot = lane >> 4;
    int cl   = (lane & 15) << 3;                 // channels cl..cl+7
    int head = (lane & 15) >> 2;

    bf16x8 xru = *(const bf16x8*)(xlr + (size_t)node * 256 + 128 + cl);
    float xr[8], at4[8];
    #pragma unroll
    for (int j = 0; j < 8; ++j) xr[j] = bf2f((ushort_t)xru[j]);
    float4 at0 = *(const float4*)(att + cl);
    float4 at1 = *(const float4*)(att + cl + 4);
    at4[0] = 0.4f*at0.x; at4[1] = 0.4f*at0.y; at4[2] = 0.4f*at0.z; at4[3] = 0.4f*at0.w;
    at4[4] = 0.4f*at1.x; at4[5] = 0.4f*at1.y; at4[6] = 0.4f*at1.z; at4[7] = 0.4f*at1.w;
    float drn = dlr6[(size_t)node * 8 + 4 + head];   // 0.6*at.xr[node]

    int e0 = row_ptr[node], e1 = row_ptr[node + 1];
    float acc[8] = {0.f,0.f,0.f,0.f,0.f,0.f,0.f,0.f};
    float suma = 0.f;
    for (int e = e0; e < e1; e += 4) {
        int ea = e + slot;
        bool va = ea < e1;
        int sa = csr_src[va ? ea : e];
        float dla = dlr6[(size_t)sa * 8 + head];     // 0.6*at.xl[sa]
        bf16x8 xua = *(const bf16x8*)(xlr + (size_t)sa * 256 + cl);
        float xa[8];
        #pragma unroll
        for (int j = 0; j < 8; ++j) xa[j] = bf2f((ushort_t)xua[j]);
        float pa = 0.f;
        #pragma unroll
        for (int j = 0; j < 8; ++j) {
            float s = xa[j] + xr[j];
            pa = fmaf(at4[j], fabsf(s), pa);         // abs is a free VOP3 modifier
        }
        pa += __shfl_xor(pa, 1); pa += __shfl_xor(pa, 2);
        float aa = va ? __expf(pa + dla + drn) : 0.f;
        suma += aa;
        #pragma unroll
        for (int j = 0; j < 8; ++j) acc[j] = fmaf(aa, xa[j], acc[j]);
    }
    // combine the four edge slots
    suma += __shfl_xor(suma, 16); suma += __shfl_xor(suma, 32);
    #pragma unroll
    for (int j = 0; j < 8; ++j) {
        acc[j] += __shfl_xor(acc[j], 16);
        acc[j] += __shfl_xor(acc[j], 32);
    }
    if (slot == 0) {
        float inv = 1.0f / (suma + 1e-16f);
        float4 ob0 = *(const float4*)(b_out + cl);
        float4 ob1 = *(const float4*)(b_out + cl + 4);
        float ob[8] = {ob0.x, ob0.y, ob0.z, ob0.w, ob1.x, ob1.y, ob1.z, ob1.w};
        short r[8];
        #pragma unroll
        for (int j = 0; j < 8; ++j) r[j] = f2bf(fmaf(acc[j], inv, ob[j]));
        *(bf16x8*)(g + (size_t)node * 128 + cl) = *(const bf16x8*)r;
    }
}

// ---------------- PairNorm column sums (bf16 g) ----------------
__global__ void colsum_k(const ushort_t* __restrict__ g, float* __restrict__ colsum) {
    __shared__ float buf[256];
    int c = threadIdx.x & 127;
    int half = threadIdx.x >> 7;
    int r0 = blockIdx.x * 256;
    int rend = min(r0 + 256, NN);
    float s = 0.f;
    for (int r = r0 + half; r < rend; r += 2)
        s += bf2f(g[(size_t)r * 128 + c]);
    buf[threadIdx.x] = s;
    __syncthreads();
    if (threadIdx.x < 128)
        atomicAdd(&colsum[c], buf[threadIdx.x] + buf[threadIdx.x + 128]);
}

// ---------------- fused pairnorm + residual + layernorm (+relu) ----------------
__global__ __launch_bounds__(256, 4)
void finalize_k(const ushort_t* __restrict__ g, const float* __restrict__ colsum,
                const ushort_t* __restrict__ ident, const float* __restrict__ lng,
                const float* __restrict__ lnb, ushort_t* __restrict__ hout_bf,
                float* __restrict__ hout_f32, int is_final)
{
    int node = blockIdx.x * 4 + (threadIdx.x >> 6);
    int lane = threadIdx.x & 63;
    int j0 = lane * 2;
    const float invN = 1.0f / (float)NN;
    const float sqrtN = sqrtf((float)NN);

    ushort2 vu = *(const ushort2*)(g + (size_t)node * 128 + j0);
    float x0 = bf2f(vu.x) - colsum[j0] * invN;
    float x1 = bf2f(vu.y) - colsum[j0 + 1] * invN;
    float ss = x0 * x0 + x1 * x1;
    ss += __shfl_xor(ss, 1);  ss += __shfl_xor(ss, 2);  ss += __shfl_xor(ss, 4);
    ss += __shfl_xor(ss, 8);  ss += __shfl_xor(ss, 16); ss += __shfl_xor(ss, 32);
    float sc = sqrtN / (sqrtf(ss) + 1e-6f);

    ushort2 idu = *(const ushort2*)(ident + (size_t)node * 128 + j0);
    float t0 = x0 * sc + bf2f(idu.x);
    float t1 = x1 * sc + bf2f(idu.y);

    float m = t0 + t1;
    m += __shfl_xor(m, 1);  m += __shfl_xor(m, 2);  m += __shfl_xor(m, 4);
    m += __shfl_xor(m, 8);  m += __shfl_xor(m, 16); m += __shfl_xor(m, 32);
    m *= (1.0f / 128.0f);
    float d0 = t0 - m, d1 = t1 - m;
    float vv = d0 * d0 + d1 * d1;
    vv += __shfl_xor(vv, 1);  vv += __shfl_xor(vv, 2);  vv += __shfl_xor(vv, 4);
    vv += __shfl_xor(vv, 8);  vv += __shfl_xor(vv, 16); vv += __shfl_xor(vv, 32);
    vv *= (1.0f / 128.0f);
    float r = rsqrtf(vv + 1e-5f);

    float y0 = d0 * r * lng[j0]     + lnb[j0];
    float y1 = d1 * r * lng[j0 + 1] + lnb[j0 + 1];
    if (is_final) {
        float2 o; o.x = y0; o.y = y1;
        *(float2*)(hout_f32 + (size_t)node * 128 + j0) = o;
    } else {
        y0 = fmaxf(y0, 0.f); y1 = fmaxf(y1, 0.f);
        ushort2 o; o.x = (ushort_t)f2bf(y0); o.y = (ushort_t)f2bf(y1);
        *(ushort2*)(hout_bf + (size_t)node * 128 + j0) = o;
    }
}

// ---------------- host launch ----------------
extern "C" void kernel_launch(void* const* d_in, const int* in_sizes, int n_in,
                              void* d_out, int out_size, void* d_ws, size_t ws_size,
                              hipStream_t stream) {
    const float* x     = (const float*)d_in[0];
    const int*   ei    = (const int*)  d_in[1];   // [2][E]
    const float* w_in  = (const float*)d_in[2];
    const float* b_in  = (const float*)d_in[3];
    const float* Wl    = (const float*)d_in[4];
    const float* bl    = (const float*)d_in[5];
    const float* Wr    = (const float*)d_in[6];
    const float* att   = (const float*)d_in[7];
    const float* b_out = (const float*)d_in[8];
    const float* Wres  = (const float*)d_in[9];
    const float* bres  = (const float*)d_in[10];
    const float* ln_g  = (const float*)d_in[11];
    const float* ln_b  = (const float*)d_in[12];

    // workspace layout (bf16 feature buffers)
    ushort_t* h     = (ushort_t*)d_ws;                 // N*128 bf16
    ushort_t* xlr   = h + (size_t)NN * 128;            // N*256 bf16
    ushort_t* ident = xlr + (size_t)NN * 256;          // N*128 bf16
    ushort_t* g     = ident + (size_t)NN * 128;        // N*128 bf16
    ushort_t* wt    = g + (size_t)NN * 128;            // 9*128*128 bf16 (transposed weights)
    int*   row_ptr = (int*)(wt + 9 * 16384);           // N+1
    int*   cursor  = row_ptr + (NN + 1);               // N     (zeroed; also deg)
    float* colsum  = (float*)(cursor + NN);            // 3*128 (zeroed)
    int*   bsum    = (int*)(colsum + 384);             // 512
    int*   csr_src = bsum + 512;                       // E
    float* dlr6    = (float*)(csr_src + NE);           // N*8 f32 (0.6*at.xl | 0.6*at.xr)
    ushort_t* Pmat = (ushort_t*)(dlr6 + (size_t)NN * 8); // 3*16*128 bf16
    float* qvec    = (float*)(Pmat + 3 * 2048);        // 3*8 f32

    const int* e_src = ei;
    const int* e_dst = ei + NE;

    hipMemsetAsync(cursor, 0, (size_t)(NN + 384) * 4, stream);

    // weight prep (once per call)
    prep_w_k<<<dim3(4, 4, 9), dim3(32, 8), 0, stream>>>(w_in, Wl, Wr, Wres, wt);
    prep_p_k<<<3, 128, 0, stream>>>(Wl, Wr, att, bl, Pmat, qvec);

    // CSR build
    const int nb = (NN + 255) / 256;             // 391
    count_k  <<<NE / 256, 256, 0, stream>>>(e_dst, cursor);
    scan1_k  <<<nb, 256, 0, stream>>>(cursor, row_ptr, bsum);
    scan2_k  <<<1, 512, 0, stream>>>(bsum, nb, row_ptr + NN);
    scan3_k  <<<nb, 256, 0, stream>>>(row_ptr, bsum, cursor);
    scatter_k<<<NE / 256, 256, 0, stream>>>(e_src, e_dst, cursor, csr_src);

    const int gx = (NN + 127) / 128;             // 782

    // h = bf16(x @ w_in + b_in)
    gemm_k<1><<<dim3(gx, 1), 256, 0, stream>>>(x, wt, 0, 0, 0,
                                               b_in, nullptr, h, 128, nullptr, NN,
                                               nullptr, nullptr, nullptr);

    for (int i = 0; i < 3; ++i) {
        // xlr = bf16(h @ [Wl | Wr] + [bl | 0]); (i>0) ident = bf16(h @ Wres + bres)
        // y==0 also emits dlr6 = h @ P + q (linear logit terms)
        gemm_k<0><<<dim3(gx, (i > 0) ? 3 : 2), 256, 0, stream>>>(
            h, wt, 1 + i, 4 + i, 7 + (i - 1),
            bl + i * 128, (i > 0) ? (bres + (i - 1) * 128) : nullptr,
            xlr, 256, ident, NN,
            Pmat + (size_t)i * 2048, qvec + i * 8, dlr6);
        gat_aggregate_k<<<NN / 4, 256, 0, stream>>>(xlr, dlr6, row_ptr, csr_src,
                                                    att + i * 128, b_out + i * 128, g);
        colsum_k<<<nb, 256, 0, stream>>>(g, colsum + i * 128);
        finalize_k<<<NN / 4, 256, 0, stream>>>(g, colsum + i * 128,
                                               (i == 0) ? h : ident,
                                               ln_g + i * 128, ln_b + i * 128,
                                               h, (float*)d_out, (i == 2) ? 1 : 0);
    }
}

// Round 3
// 708.782 us; speedup vs baseline: 1.0152x; 1.0152x over previous
//
#include <hip/hip_runtime.h>
#include <hip/hip_bf16.h>

#define NN 100000
#define NE 800000
// D=128, H=4, C=32

typedef __attribute__((ext_vector_type(8))) short bf16x8;
typedef __attribute__((ext_vector_type(4))) float f32x4;
typedef unsigned short ushort_t;

static __device__ __forceinline__ short f2bf(float f) {
    union { float f; unsigned u; } v; v.f = f;
    unsigned u = v.u;
    unsigned r = u + 0x7FFFu + ((u >> 16) & 1u);   // RNE
    return (short)(r >> 16);
}
static __device__ __forceinline__ float bf2f(unsigned short u) {
    union { unsigned u; float f; } v; v.u = ((unsigned)u) << 16;
    return v.f;
}

// ---------------- weight prep: W[k][c] fp32 -> Wt[c][k] bf16, 9 matrices ------------
__global__ void prep_w_k(const float* __restrict__ w_in, const float* __restrict__ Wl,
                         const float* __restrict__ Wr, const float* __restrict__ Wres,
                         ushort_t* __restrict__ wt)
{
    __shared__ float tile[32][33];
    int m = blockIdx.z;
    const float* src;
    if (m == 0)      src = w_in;
    else if (m < 4)  src = Wl + (size_t)(m - 1) * 16384;
    else if (m < 7)  src = Wr + (size_t)(m - 4) * 16384;
    else             src = Wres + (size_t)(m - 7) * 16384;
    ushort_t* dst = wt + (size_t)m * 16384;

    int tx = threadIdx.x, ty = threadIdx.y;
    int k0 = blockIdx.x * 32, c0 = blockIdx.y * 32;
    #pragma unroll
    for (int j = 0; j < 4; ++j)
        tile[ty + 8 * j][tx] = src[(size_t)(k0 + ty + 8 * j) * 128 + c0 + tx];
    __syncthreads();
    #pragma unroll
    for (int j = 0; j < 4; ++j)
        dst[(size_t)(c0 + ty + 8 * j) * 128 + k0 + tx] = (ushort_t)f2bf(tile[tx][ty + 8 * j]);
}

// ---------------- P prep: P[i] = Wl*at6 (128x4, padded to 16 cols, [col][k] bf16),
//                  q[i][h] = bl . at6 per head ------------------------------------
// leaky(s) = 0.6 s + 0.4 |s|  =>  logit = 0.6*at.xl[src] + 0.6*at.xr[dst] + sum 0.4*at*|s|.
// The 0.6*at.xr[dst] term is constant per destination -> cancels in softmax EXACTLY.
// Only dl[src] = 0.6*at.xl[src] survives; computed as h @ P + q inside gemm_k.
__global__ void prep_p_k(const float* __restrict__ Wl, const float* __restrict__ att,
                         const float* __restrict__ bl,
                         ushort_t* __restrict__ Pmat, float* __restrict__ qvec)
{
    int i = blockIdx.x;          // layer
    int k = threadIdx.x;         // 0..127
    __shared__ float at6[128];
    at6[k] = 0.6f * att[i * 128 + k];
    __syncthreads();
    const float* wl = Wl + (size_t)i * 16384 + (size_t)k * 128;
    float pl[4] = {0.f, 0.f, 0.f, 0.f};
    #pragma unroll
    for (int c4 = 0; c4 < 32; ++c4) {
        float4 w = *(const float4*)(wl + c4 * 4);
        float t = fmaf(w.x, at6[4 * c4],
                  fmaf(w.y, at6[4 * c4 + 1],
                  fmaf(w.z, at6[4 * c4 + 2], w.w * at6[4 * c4 + 3])));
        pl[c4 >> 3] += t;
    }
    ushort_t* P = Pmat + (size_t)i * 2048;       // [16 cols][128 k]
    #pragma unroll
    for (int h = 0; h < 4; ++h)
        P[(size_t)h * 128 + k] = (ushort_t)f2bf(pl[h]);
    #pragma unroll
    for (int h = 4; h < 16; ++h)
        P[(size_t)h * 128 + k] = 0;
    if (k < 4) {
        float s = 0.f;
        for (int c = 0; c < 32; ++c)
            s += bl[i * 128 + k * 32 + c] * 0.6f * att[i * 128 + k * 32 + c];
        qvec[i * 4 + k] = s;
    }
}

// ---------------- GEMM: 128-row tiles, B-tile staged dense in LDS ----------------
// out = A[M x 128] @ wt[w_y]^T + bias.  y==0 additionally computes
// dl4[N x 4] = A @ P + q via 8 extra MFMAs (A fragments already in registers).
template<int A_FP32>
__global__ __launch_bounds__(256, 4)
void gemm_k(const void* __restrict__ Av, const ushort_t* __restrict__ wt,
            int w0, int w1, int w2,
            const float* __restrict__ bias0, const float* __restrict__ bias2,
            ushort_t* __restrict__ out0, int Dout0, ushort_t* __restrict__ out2, int M,
            const ushort_t* __restrict__ Pmat, const float* __restrict__ qvec,
            float* __restrict__ dl4)
{
    __shared__ short Bs[128][136];   // B-tile [col][k]; reused as C-tile [row][col]
    __shared__ short Ps[16][136];    // P-tile [col][k]
    const int tid = threadIdx.x;
    const int rowBlk = blockIdx.x * 128;
    const int y = blockIdx.y;
    const ushort_t* W = wt + (size_t)((y == 0) ? w0 : (y == 1) ? w1 : w2) * 16384;
    const float* bias = (y == 0) ? bias0 : ((y == 2) ? bias2 : nullptr);
    ushort_t* out = (y == 2) ? out2 : out0;
    const int Dout   = (y == 2) ? 128 : Dout0;
    const int colOff = (y == 1) ? 128 : 0;
    const bool doP = (y == 0) && (Pmat != nullptr);

    const int wave = tid >> 6;
    const int lane = tid & 63;
    const int quad = lane >> 4;
    const int lr   = lane & 15;

    const int row0 = rowBlk + wave * 32 + lr;       // A fragment rows
    const int row1 = row0 + 16;

    // ---- A fragments direct from global (issued first, latency-hidden) ----
    bf16x8 afr[4][2];
    #pragma unroll
    for (int ks = 0; ks < 4; ++ks) {
        int kb = ks * 32 + quad * 8;
        bf16x8 a0 = (bf16x8)0, a1 = (bf16x8)0;
        if (A_FP32) {
            const float* A = (const float*)Av;
            if (row0 < M) {
                float4 v0 = *(const float4*)(A + (size_t)row0 * 128 + kb);
                float4 v1 = *(const float4*)(A + (size_t)row0 * 128 + kb + 4);
                a0[0]=f2bf(v0.x); a0[1]=f2bf(v0.y); a0[2]=f2bf(v0.z); a0[3]=f2bf(v0.w);
                a0[4]=f2bf(v1.x); a0[5]=f2bf(v1.y); a0[6]=f2bf(v1.z); a0[7]=f2bf(v1.w);
            }
            if (row1 < M) {
                float4 v0 = *(const float4*)(A + (size_t)row1 * 128 + kb);
                float4 v1 = *(const float4*)(A + (size_t)row1 * 128 + kb + 4);
                a1[0]=f2bf(v0.x); a1[1]=f2bf(v0.y); a1[2]=f2bf(v0.z); a1[3]=f2bf(v0.w);
                a1[4]=f2bf(v1.x); a1[5]=f2bf(v1.y); a1[6]=f2bf(v1.z); a1[7]=f2bf(v1.w);
            }
        } else {
            const ushort_t* A = (const ushort_t*)Av;
            if (row0 < M) a0 = *(const bf16x8*)(A + (size_t)row0 * 128 + kb);
            if (row1 < M) a1 = *(const bf16x8*)(A + (size_t)row1 * 128 + kb);
        }
        afr[ks][0] = a0; afr[ks][1] = a1;
    }

    // ---- stage B-tile densely; stage P-tile if needed ----
    #pragma unroll
    for (int i = 0; i < 8; ++i) {
        int linear = tid + 256 * i;              // 2048 16B chunks
        int r  = linear >> 4;
        int c8 = (linear & 15) << 3;
        *(bf16x8*)&Bs[r][c8] = *(const bf16x8*)(W + (size_t)r * 128 + c8);
    }
    if (doP) {
        int r  = tid >> 4;                       // 0..15
        int c8 = (tid & 15) << 3;
        *(bf16x8*)&Ps[r][c8] = *(const bf16x8*)(Pmat + (size_t)r * 128 + c8);
    }
    __syncthreads();

    f32x4 acc[2][8];
    #pragma unroll
    for (int mt = 0; mt < 2; ++mt)
        #pragma unroll
        for (int nt = 0; nt < 8; ++nt) acc[mt][nt] = (f32x4)(0.0f);
    f32x4 accP[2];
    accP[0] = (f32x4)(0.0f); accP[1] = (f32x4)(0.0f);

    #pragma unroll
    for (int ks = 0; ks < 4; ++ks) {
        int kb = ks * 32 + quad * 8;
        #pragma unroll
        for (int nt = 0; nt < 8; ++nt) {
            bf16x8 b = *(const bf16x8*)&Bs[nt * 16 + lr][kb];
            acc[0][nt] = __builtin_amdgcn_mfma_f32_16x16x32_bf16(afr[ks][0], b, acc[0][nt], 0, 0, 0);
            acc[1][nt] = __builtin_amdgcn_mfma_f32_16x16x32_bf16(afr[ks][1], b, acc[1][nt], 0, 0, 0);
        }
        if (doP) {
            bf16x8 pb = *(const bf16x8*)&Ps[lr][kb];
            accP[0] = __builtin_amdgcn_mfma_f32_16x16x32_bf16(afr[ks][0], pb, accP[0], 0, 0, 0);
            accP[1] = __builtin_amdgcn_mfma_f32_16x16x32_bf16(afr[ks][1], pb, accP[1], 0, 0, 0);
        }
    }

    // ---- dl4 epilogue (cols 0..3 of the P-tile): row-scattered f32 stores ----
    if (doP && lr < 4) {
        float qv = qvec[lr];
        #pragma unroll
        for (int mt = 0; mt < 2; ++mt)
            #pragma unroll
            for (int r = 0; r < 4; ++r) {
                int row = rowBlk + wave * 32 + mt * 16 + quad * 4 + r;
                if (row < M) dl4[(size_t)row * 4 + lr] = accP[mt][r] + qv;
            }
    }

    // ---- epilogue: reuse Bs as C-tile; C/D layout col = lane&15, row = quad*4 + reg
    __syncthreads();                             // all waves done reading B
    #pragma unroll
    for (int mt = 0; mt < 2; ++mt)
        #pragma unroll
        for (int nt = 0; nt < 8; ++nt) {
            int col = nt * 16 + lr;
            float b = bias ? bias[col] : 0.0f;
            #pragma unroll
            for (int r = 0; r < 4; ++r) {
                int row = wave * 32 + mt * 16 + quad * 4 + r;
                Bs[row][col] = f2bf(acc[mt][nt][r] + b);
            }
        }
    __syncthreads();
    #pragma unroll
    for (int i = 0; i < 8; ++i) {
        int linear = tid + 256 * i;              // 2048 16B chunks
        int r  = linear >> 4;
        int c8 = (linear & 15) << 3;
        int gr = rowBlk + r;
        if (gr < M)
            *(bf16x8*)(out + (size_t)gr * Dout + colOff + c8) = *(const bf16x8*)&Bs[r][c8];
    }
}

// ---------------- CSR build ----------------
__global__ void count_k(const int* __restrict__ dst, int* __restrict__ deg) {
    int e = blockIdx.x * 256 + threadIdx.x;
    if (e < NE) atomicAdd(&deg[dst[e]], 1);
}

__global__ void scan1_k(const int* __restrict__ deg, int* __restrict__ excl,
                        int* __restrict__ bsum) {
    __shared__ int buf[256];
    int i = blockIdx.x * 256 + threadIdx.x;
    int v = (i < NN) ? deg[i] : 0;
    buf[threadIdx.x] = v; __syncthreads();
    for (int off = 1; off < 256; off <<= 1) {
        int t = (threadIdx.x >= off) ? buf[threadIdx.x - off] : 0;
        __syncthreads();
        buf[threadIdx.x] += t;
        __syncthreads();
    }
    if (i < NN) excl[i] = buf[threadIdx.x] - v;
    if (threadIdx.x == 255) bsum[blockIdx.x] = buf[255];
}

__global__ void scan2_k(int* __restrict__ bsum, int nb, int* __restrict__ total) {
    __shared__ int buf[512];
    int v = (threadIdx.x < nb) ? bsum[threadIdx.x] : 0;
    buf[threadIdx.x] = v; __syncthreads();
    for (int off = 1; off < 512; off <<= 1) {
        int t = (threadIdx.x >= off) ? buf[threadIdx.x - off] : 0;
        __syncthreads();
        buf[threadIdx.x] += t;
        __syncthreads();
    }
    if (threadIdx.x < nb) bsum[threadIdx.x] = buf[threadIdx.x] - v;  // exclusive base
    if (threadIdx.x == 511) *total = buf[511];
}

__global__ void scan3_k(int* __restrict__ row_ptr, const int* __restrict__ bsum,
                        int* __restrict__ cursor) {
    int i = blockIdx.x * 256 + threadIdx.x;
    if (i < NN) {
        int v = row_ptr[i] + bsum[blockIdx.x];
        row_ptr[i] = v;
        cursor[i]  = v;
    }
}

__global__ void scatter_k(const int* __restrict__ src, const int* __restrict__ dst,
                          int* __restrict__ cursor, int* __restrict__ csr_src) {
    int e = blockIdx.x * 256 + threadIdx.x;
    if (e < NE) {
        int p = atomicAdd(&cursor[dst[e]], 1);
        csr_src[p] = src[e];
    }
}

// ---------------- GATv2 aggregate: one wave per destination node, 8 edges/iter --------
// R0 skeleton (two independent gather chains/iter, (256,8) bounds) with the
// abs-decomposed logit: per channel add + fma(|s|) replaces add+mul+max+fma.
// Per-edge linear term dl4[src] gathered from a 1.6 MB L2-resident table;
// destination linear term cancels in softmax (per-dst constant) and is dropped.
__global__ __launch_bounds__(256, 8)
void gat_aggregate_k(const ushort_t* __restrict__ xlr, const float* __restrict__ dl4,
                     const int* __restrict__ row_ptr, const int* __restrict__ csr_src,
                     const float* __restrict__ att, const float* __restrict__ b_out,
                     ushort_t* __restrict__ g)
{
    int node = blockIdx.x * 4 + (threadIdx.x >> 6);
    int lane = threadIdx.x & 63;
    int slot = lane >> 4;
    int cl   = (lane & 15) << 3;                 // channels cl..cl+7
    int head = (lane & 15) >> 2;
    bf16x8 xru = *(const bf16x8*)(xlr + (size_t)node * 256 + 128 + cl);
    float xr[8], at4[8];
    #pragma unroll
    for (int j = 0; j < 8; ++j) xr[j] = bf2f((ushort_t)xru[j]);
    float4 at0 = *(const float4*)(att + cl);
    float4 at1 = *(const float4*)(att + cl + 4);
    at4[0] = 0.4f*at0.x; at4[1] = 0.4f*at0.y; at4[2] = 0.4f*at0.z; at4[3] = 0.4f*at0.w;
    at4[4] = 0.4f*at1.x; at4[5] = 0.4f*at1.y; at4[6] = 0.4f*at1.z; at4[7] = 0.4f*at1.w;

    int e0 = row_ptr[node], e1 = row_ptr[node + 1];
    float acc[8] = {0.f,0.f,0.f,0.f,0.f,0.f,0.f,0.f};
    float suma = 0.f;
    for (int e = e0; e < e1; e += 8) {
        int ea = e + slot, eb = e + 4 + slot;
        bool va = ea < e1, vb = eb < e1;
        int sa = csr_src[va ? ea : e];
        int sb = csr_src[vb ? eb : e];
        float dla = dl4[(size_t)sa * 4 + head];
        float dlb = dl4[(size_t)sb * 4 + head];
        bf16x8 xua = *(const bf16x8*)(xlr + (size_t)sa * 256 + cl);
        bf16x8 xub = *(const bf16x8*)(xlr + (size_t)sb * 256 + cl);
        float xa[8], xb[8];
        #pragma unroll
        for (int j = 0; j < 8; ++j) { xa[j] = bf2f((ushort_t)xua[j]); xb[j] = bf2f((ushort_t)xub[j]); }
        float pa = 0.f, pb = 0.f;
        #pragma unroll
        for (int j = 0; j < 8; ++j) {
            float sva = xa[j] + xr[j];
            float svb = xb[j] + xr[j];
            pa = fmaf(at4[j], fabsf(sva), pa);   // abs is a free VOP3 modifier
            pb = fmaf(at4[j], fabsf(svb), pb);
        }
        pa += __shfl_xor(pa, 1); pa += __shfl_xor(pa, 2);
        pb += __shfl_xor(pb, 1); pb += __shfl_xor(pb, 2);
        float aa = va ? __expf(pa + dla) : 0.f;
        float ab = vb ? __expf(pb + dlb) : 0.f;
        suma += aa + ab;
        #pragma unroll
        for (int j = 0; j < 8; ++j) acc[j] = fmaf(aa, xa[j], fmaf(ab, xb[j], acc[j]));
    }
    // combine the four edge slots
    suma += __shfl_xor(suma, 16); suma += __shfl_xor(suma, 32);
    #pragma unroll
    for (int j = 0; j < 8; ++j) {
        acc[j] += __shfl_xor(acc[j], 16);
        acc[j] += __shfl_xor(acc[j], 32);
    }
    if (slot == 0) {
        float inv = 1.0f / (suma + 1e-16f);
        float4 ob0 = *(const float4*)(b_out + cl);
        float4 ob1 = *(const float4*)(b_out + cl + 4);
        float ob[8] = {ob0.x, ob0.y, ob0.z, ob0.w, ob1.x, ob1.y, ob1.z, ob1.w};
        short r[8];
        #pragma unroll
        for (int j = 0; j < 8; ++j) r[j] = f2bf(fmaf(acc[j], inv, ob[j]));
        *(bf16x8*)(g + (size_t)node * 128 + cl) = *(const bf16x8*)r;
    }
}

// ---------------- PairNorm column sums (bf16 g) ----------------
__global__ void colsum_k(const ushort_t* __restrict__ g, float* __restrict__ colsum) {
    __shared__ float buf[256];
    int c = threadIdx.x & 127;
    int half = threadIdx.x >> 7;
    int r0 = blockIdx.x * 256;
    int rend = min(r0 + 256, NN);
    float s = 0.f;
    for (int r = r0 + half; r < rend; r += 2)
        s += bf2f(g[(size_t)r * 128 + c]);
    buf[threadIdx.x] = s;
    __syncthreads();
    if (threadIdx.x < 128)
        atomicAdd(&colsum[c], buf[threadIdx.x] + buf[threadIdx.x + 128]);
}

// ---------------- fused pairnorm + residual + layernorm (+relu) ----------------
__global__ __launch_bounds__(256, 4)
void finalize_k(const ushort_t* __restrict__ g, const float* __restrict__ colsum,
                const ushort_t* __restrict__ ident, const float* __restrict__ lng,
                const float* __restrict__ lnb, ushort_t* __restrict__ hout_bf,
                float* __restrict__ hout_f32, int is_final)
{
    int node = blockIdx.x * 4 + (threadIdx.x >> 6);
    int lane = threadIdx.x & 63;
    int j0 = lane * 2;
    const float invN = 1.0f / (float)NN;
    const float sqrtN = sqrtf((float)NN);

    ushort2 vu = *(const ushort2*)(g + (size_t)node * 128 + j0);
    float x0 = bf2f(vu.x) - colsum[j0] * invN;
    float x1 = bf2f(vu.y) - colsum[j0 + 1] * invN;
    float ss = x0 * x0 + x1 * x1;
    ss += __shfl_xor(ss, 1);  ss += __shfl_xor(ss, 2);  ss += __shfl_xor(ss, 4);
    ss += __shfl_xor(ss, 8);  ss += __shfl_xor(ss, 16); ss += __shfl_xor(ss, 32);
    float sc = sqrtN / (sqrtf(ss) + 1e-6f);

    ushort2 idu = *(const ushort2*)(ident + (size_t)node * 128 + j0);
    float t0 = x0 * sc + bf2f(idu.x);
    float t1 = x1 * sc + bf2f(idu.y);

    float m = t0 + t1;
    m += __shfl_xor(m, 1);  m += __shfl_xor(m, 2);  m += __shfl_xor(m, 4);
    m += __shfl_xor(m, 8);  m += __shfl_xor(m, 16); m += __shfl_xor(m, 32);
    m *= (1.0f / 128.0f);
    float d0 = t0 - m, d1 = t1 - m;
    float vv = d0 * d0 + d1 * d1;
    vv += __shfl_xor(vv, 1);  vv += __shfl_xor(vv, 2);  vv += __shfl_xor(vv, 4);
    vv += __shfl_xor(vv, 8);  vv += __shfl_xor(vv, 16); vv += __shfl_xor(vv, 32);
    vv *= (1.0f / 128.0f);
    float r = rsqrtf(vv + 1e-5f);

    float y0 = d0 * r * lng[j0]     + lnb[j0];
    float y1 = d1 * r * lng[j0 + 1] + lnb[j0 + 1];
    if (is_final) {
        float2 o; o.x = y0; o.y = y1;
        *(float2*)(hout_f32 + (size_t)node * 128 + j0) = o;
    } else {
        y0 = fmaxf(y0, 0.f); y1 = fmaxf(y1, 0.f);
        ushort2 o; o.x = (ushort_t)f2bf(y0); o.y = (ushort_t)f2bf(y1);
        *(ushort2*)(hout_bf + (size_t)node * 128 + j0) = o;
    }
}

// ---------------- host launch ----------------
extern "C" void kernel_launch(void* const* d_in, const int* in_sizes, int n_in,
                              void* d_out, int out_size, void* d_ws, size_t ws_size,
                              hipStream_t stream) {
    const float* x     = (const float*)d_in[0];
    const int*   ei    = (const int*)  d_in[1];   // [2][E]
    const float* w_in  = (const float*)d_in[2];
    const float* b_in  = (const float*)d_in[3];
    const float* Wl    = (const float*)d_in[4];
    const float* bl    = (const float*)d_in[5];
    const float* Wr    = (const float*)d_in[6];
    const float* att   = (const float*)d_in[7];
    const float* b_out = (const float*)d_in[8];
    const float* Wres  = (const float*)d_in[9];
    const float* bres  = (const float*)d_in[10];
    const float* ln_g  = (const float*)d_in[11];
    const float* ln_b  = (const float*)d_in[12];

    // workspace layout (bf16 feature buffers)
    ushort_t* h     = (ushort_t*)d_ws;                 // N*128 bf16
    ushort_t* xlr   = h + (size_t)NN * 128;            // N*256 bf16
    ushort_t* ident = xlr + (size_t)NN * 256;          // N*128 bf16
    ushort_t* g     = ident + (size_t)NN * 128;        // N*128 bf16
    ushort_t* wt    = g + (size_t)NN * 128;            // 9*128*128 bf16 (transposed weights)
    int*   row_ptr = (int*)(wt + 9 * 16384);           // N+1
    int*   cursor  = row_ptr + (NN + 1);               // N     (zeroed; also deg)
    float* colsum  = (float*)(cursor + NN);            // 3*128 (zeroed)
    int*   bsum    = (int*)(colsum + 384);             // 512
    int*   csr_src = bsum + 512;                       // E
    float* dl4     = (float*)(csr_src + NE);           // N*4 f32 (0.6*at.xl per head)
    ushort_t* Pmat = (ushort_t*)(dl4 + (size_t)NN * 4); // 3*16*128 bf16
    float* qvec    = (float*)(Pmat + 3 * 2048);        // 3*4 f32

    const int* e_src = ei;
    const int* e_dst = ei + NE;

    hipMemsetAsync(cursor, 0, (size_t)(NN + 384) * 4, stream);

    // weight prep (once per call)
    prep_w_k<<<dim3(4, 4, 9), dim3(32, 8), 0, stream>>>(w_in, Wl, Wr, Wres, wt);
    prep_p_k<<<3, 128, 0, stream>>>(Wl, att, bl, Pmat, qvec);

    // CSR build
    const int nb = (NN + 255) / 256;             // 391
    count_k  <<<NE / 256, 256, 0, stream>>>(e_dst, cursor);
    scan1_k  <<<nb, 256, 0, stream>>>(cursor, row_ptr, bsum);
    scan2_k  <<<1, 512, 0, stream>>>(bsum, nb, row_ptr + NN);
    scan3_k  <<<nb, 256, 0, stream>>>(row_ptr, bsum, cursor);
    scatter_k<<<NE / 256, 256, 0, stream>>>(e_src, e_dst, cursor, csr_src);

    const int gx = (NN + 127) / 128;             // 782

    // h = bf16(x @ w_in + b_in)
    gemm_k<1><<<dim3(gx, 1), 256, 0, stream>>>(x, wt, 0, 0, 0,
                                               b_in, nullptr, h, 128, nullptr, NN,
                                               nullptr, nullptr, nullptr);

    for (int i = 0; i < 3; ++i) {
        // xlr = bf16(h @ [Wl | Wr] + [bl | 0]); (i>0) ident = bf16(h @ Wres + bres)
        // y==0 also emits dl4 = h @ P + q (source-side linear logit term)
        gemm_k<0><<<dim3(gx, (i > 0) ? 3 : 2), 256, 0, stream>>>(
            h, wt, 1 + i, 4 + i, 7 + (i - 1),
            bl + i * 128, (i > 0) ? (bres + (i - 1) * 128) : nullptr,
            xlr, 256, ident, NN,
            Pmat + (size_t)i * 2048, qvec + i * 4, dl4);
        gat_aggregate_k<<<NN / 4, 256, 0, stream>>>(xlr, dl4, row_ptr, csr_src,
                                                    att + i * 128, b_out + i * 128, g);
        colsum_k<<<nb, 256, 0, stream>>>(g, colsum + i * 128);
        finalize_k<<<NN / 4, 256, 0, stream>>>(g, colsum + i * 128,
                                               (i == 0) ? h : ident,
                                               ln_g + i * 128, ln_b + i * 128,
                                               h, (float*)d_out, (i == 2) ? 1 : 0);
    }
}

// Round 4
// 646.906 us; speedup vs baseline: 1.1124x; 1.0956x over previous
//
#include <hip/hip_runtime.h>
#include <hip/hip_bf16.h>

#define NN 100000
#define NE 800000
// D=128, H=4, C=32

typedef __attribute__((ext_vector_type(8))) short bf16x8;
typedef __attribute__((ext_vector_type(4))) float f32x4;
typedef unsigned short ushort_t;

static __device__ __forceinline__ short f2bf(float f) {
    union { float f; unsigned u; } v; v.f = f;
    unsigned u = v.u;
    unsigned r = u + 0x7FFFu + ((u >> 16) & 1u);   // RNE
    return (short)(r >> 16);
}
static __device__ __forceinline__ float bf2f(unsigned short u) {
    union { unsigned u; float f; } v; v.u = ((unsigned)u) << 16;
    return v.f;
}

// ---------------- weight prep: W[k][c] fp32 -> Wt[c][k] bf16, 9 matrices ------------
__global__ void prep_w_k(const float* __restrict__ w_in, const float* __restrict__ Wl,
                         const float* __restrict__ Wr, const float* __restrict__ Wres,
                         ushort_t* __restrict__ wt)
{
    __shared__ float tile[32][33];
    int m = blockIdx.z;
    const float* src;
    if (m == 0)      src = w_in;
    else if (m < 4)  src = Wl + (size_t)(m - 1) * 16384;
    else if (m < 7)  src = Wr + (size_t)(m - 4) * 16384;
    else             src = Wres + (size_t)(m - 7) * 16384;
    ushort_t* dst = wt + (size_t)m * 16384;

    int tx = threadIdx.x, ty = threadIdx.y;
    int k0 = blockIdx.x * 32, c0 = blockIdx.y * 32;
    #pragma unroll
    for (int j = 0; j < 4; ++j)
        tile[ty + 8 * j][tx] = src[(size_t)(k0 + ty + 8 * j) * 128 + c0 + tx];
    __syncthreads();
    #pragma unroll
    for (int j = 0; j < 4; ++j)
        dst[(size_t)(c0 + ty + 8 * j) * 128 + k0 + tx] = (ushort_t)f2bf(tile[tx][ty + 8 * j]);
}

// ---------------- GEMM: 128-row tiles, B-tile staged dense in LDS ----------------
// out = A[M x 128] @ wt[w_y]^T + bias. A fragments direct from global;
// B staged densely (pre-transposed wt -> straight copy, no bank conflicts);
// LDS tile reused for the C epilogue.
// blockIdx.y: 0 -> wt[w0] (+bias0) into out0 cols [0,128)
//             1 -> wt[w1] (no bias) into out0 cols [128,256)
//             2 -> wt[w2] (+bias2) into out2 (Dout=128)
template<int A_FP32>
__global__ __launch_bounds__(256, 4)
void gemm_k(const void* __restrict__ Av, const ushort_t* __restrict__ wt,
            int w0, int w1, int w2,
            const float* __restrict__ bias0, const float* __restrict__ bias2,
            ushort_t* __restrict__ out0, int Dout0, ushort_t* __restrict__ out2, int M)
{
    __shared__ short Bs[128][136];   // B-tile [col][k]; reused as C-tile [row][col]
    const int tid = threadIdx.x;
    const int rowBlk = blockIdx.x * 128;
    const int y = blockIdx.y;
    const ushort_t* W = wt + (size_t)((y == 0) ? w0 : (y == 1) ? w1 : w2) * 16384;
    const float* bias = (y == 0) ? bias0 : ((y == 2) ? bias2 : nullptr);
    ushort_t* out = (y == 2) ? out2 : out0;
    const int Dout   = (y == 2) ? 128 : Dout0;
    const int colOff = (y == 1) ? 128 : 0;

    const int wave = tid >> 6;
    const int lane = tid & 63;
    const int quad = lane >> 4;
    const int lr   = lane & 15;

    const int row0 = rowBlk + wave * 32 + lr;       // A fragment rows
    const int row1 = row0 + 16;

    // ---- A fragments direct from global (issued first, latency-hidden) ----
    bf16x8 afr[4][2];
    #pragma unroll
    for (int ks = 0; ks < 4; ++ks) {
        int kb = ks * 32 + quad * 8;
        bf16x8 a0 = (bf16x8)0, a1 = (bf16x8)0;
        if (A_FP32) {
            const float* A = (const float*)Av;
            if (row0 < M) {
                float4 v0 = *(const float4*)(A + (size_t)row0 * 128 + kb);
                float4 v1 = *(const float4*)(A + (size_t)row0 * 128 + kb + 4);
                a0[0]=f2bf(v0.x); a0[1]=f2bf(v0.y); a0[2]=f2bf(v0.z); a0[3]=f2bf(v0.w);
                a0[4]=f2bf(v1.x); a0[5]=f2bf(v1.y); a0[6]=f2bf(v1.z); a0[7]=f2bf(v1.w);
            }
            if (row1 < M) {
                float4 v0 = *(const float4*)(A + (size_t)row1 * 128 + kb);
                float4 v1 = *(const float4*)(A + (size_t)row1 * 128 + kb + 4);
                a1[0]=f2bf(v0.x); a1[1]=f2bf(v0.y); a1[2]=f2bf(v0.z); a1[3]=f2bf(v0.w);
                a1[4]=f2bf(v1.x); a1[5]=f2bf(v1.y); a1[6]=f2bf(v1.z); a1[7]=f2bf(v1.w);
            }
        } else {
            const ushort_t* A = (const ushort_t*)Av;
            if (row0 < M) a0 = *(const bf16x8*)(A + (size_t)row0 * 128 + kb);
            if (row1 < M) a1 = *(const bf16x8*)(A + (size_t)row1 * 128 + kb);
        }
        afr[ks][0] = a0; afr[ks][1] = a1;
    }

    // ---- stage B-tile densely: global 16B/lane contiguous -> LDS rows ----
    #pragma unroll
    for (int i = 0; i < 8; ++i) {
        int linear = tid + 256 * i;              // 2048 16B chunks
        int r  = linear >> 4;
        int c8 = (linear & 15) << 3;
        *(bf16x8*)&Bs[r][c8] = *(const bf16x8*)(W + (size_t)r * 128 + c8);
    }
    __syncthreads();

    f32x4 acc[2][8];
    #pragma unroll
    for (int mt = 0; mt < 2; ++mt)
        #pragma unroll
        for (int nt = 0; nt < 8; ++nt) acc[mt][nt] = (f32x4)(0.0f);

    #pragma unroll
    for (int ks = 0; ks < 4; ++ks) {
        int kb = ks * 32 + quad * 8;
        #pragma unroll
        for (int nt = 0; nt < 8; ++nt) {
            bf16x8 b = *(const bf16x8*)&Bs[nt * 16 + lr][kb];
            acc[0][nt] = __builtin_amdgcn_mfma_f32_16x16x32_bf16(afr[ks][0], b, acc[0][nt], 0, 0, 0);
            acc[1][nt] = __builtin_amdgcn_mfma_f32_16x16x32_bf16(afr[ks][1], b, acc[1][nt], 0, 0, 0);
        }
    }

    // ---- epilogue: reuse Bs as C-tile; C/D layout col = lane&15, row = quad*4 + reg
    __syncthreads();                             // all waves done reading B
    #pragma unroll
    for (int mt = 0; mt < 2; ++mt)
        #pragma unroll
        for (int nt = 0; nt < 8; ++nt) {
            int col = nt * 16 + lr;
            float b = bias ? bias[col] : 0.0f;
            #pragma unroll
            for (int r = 0; r < 4; ++r) {
                int row = wave * 32 + mt * 16 + quad * 4 + r;
                Bs[row][col] = f2bf(acc[mt][nt][r] + b);
            }
        }
    __syncthreads();
    #pragma unroll
    for (int i = 0; i < 8; ++i) {
        int linear = tid + 256 * i;              // 2048 16B chunks
        int r  = linear >> 4;
        int c8 = (linear & 15) << 3;
        int gr = rowBlk + r;
        if (gr < M)
            *(bf16x8*)(out + (size_t)gr * Dout + colOff + c8) = *(const bf16x8*)&Bs[r][c8];
    }
}

// ---------------- CSR build ----------------
__global__ void count_k(const int* __restrict__ dst, int* __restrict__ deg) {
    int e = blockIdx.x * 256 + threadIdx.x;
    if (e < NE) atomicAdd(&deg[dst[e]], 1);
}

__global__ void scan1_k(const int* __restrict__ deg, int* __restrict__ excl,
                        int* __restrict__ bsum) {
    __shared__ int buf[256];
    int i = blockIdx.x * 256 + threadIdx.x;
    int v = (i < NN) ? deg[i] : 0;
    buf[threadIdx.x] = v; __syncthreads();
    for (int off = 1; off < 256; off <<= 1) {
        int t = (threadIdx.x >= off) ? buf[threadIdx.x - off] : 0;
        __syncthreads();
        buf[threadIdx.x] += t;
        __syncthreads();
    }
    if (i < NN) excl[i] = buf[threadIdx.x] - v;
    if (threadIdx.x == 255) bsum[blockIdx.x] = buf[255];
}

__global__ void scan2_k(int* __restrict__ bsum, int nb, int* __restrict__ total) {
    __shared__ int buf[512];
    int v = (threadIdx.x < nb) ? bsum[threadIdx.x] : 0;
    buf[threadIdx.x] = v; __syncthreads();
    for (int off = 1; off < 512; off <<= 1) {
        int t = (threadIdx.x >= off) ? buf[threadIdx.x - off] : 0;
        __syncthreads();
        buf[threadIdx.x] += t;
        __syncthreads();
    }
    if (threadIdx.x < nb) bsum[threadIdx.x] = buf[threadIdx.x] - v;  // exclusive base
    if (threadIdx.x == 511) *total = buf[511];
}

__global__ void scan3_k(int* __restrict__ row_ptr, const int* __restrict__ bsum,
                        int* __restrict__ cursor) {
    int i = blockIdx.x * 256 + threadIdx.x;
    if (i < NN) {
        int v = row_ptr[i] + bsum[blockIdx.x];
        row_ptr[i] = v;
        cursor[i]  = v;
    }
}

__global__ void scatter_k(const int* __restrict__ src, const int* __restrict__ dst,
                          int* __restrict__ cursor, int* __restrict__ csr_src) {
    int e = blockIdx.x * 256 + threadIdx.x;
    if (e < NE) {
        int p = atomicAdd(&cursor[dst[e]], 1);
        csr_src[p] = src[e];
    }
}

// ---------------- GATv2 aggregate: one wave per destination node, 8 edges/iter --------
// R0 skeleton exactly (two independent gather chains, (256,8) bounds).
// Logit via abs-decomposition, fully in registers:
//   leaky(s) = 0.6 s + 0.4|s|;  logit = sum 0.4 at |s| + 0.6 at.xl[src] (+ per-dst const,
//   which cancels in softmax). Both dots share the SAME constant vector at4 = 0.4*at:
//   logit = pa + 1.5*qa with pa = sum at4|s|, qa = sum at4*xa.
// vs R0's leaky path this removes one mul+max per channel (6 -> 5 ops) with no new
// memory traffic, no extra constants, no extra shuffles (combine folded pre-reduce).
__global__ __launch_bounds__(256, 8)
void gat_aggregate_k(const ushort_t* __restrict__ xlr, const int* __restrict__ row_ptr,
                     const int* __restrict__ csr_src, const float* __restrict__ att,
                     const float* __restrict__ b_out, ushort_t* __restrict__ g)
{
    int node = blockIdx.x * 4 + (threadIdx.x >> 6);
    int lane = threadIdx.x & 63;
    int slot = lane >> 4;
    int cl   = (lane & 15) << 3;                 // channels cl..cl+7
    bf16x8 xru = *(const bf16x8*)(xlr + (size_t)node * 256 + 128 + cl);
    float xr[8], at4[8];
    #pragma unroll
    for (int j = 0; j < 8; ++j) xr[j] = bf2f((ushort_t)xru[j]);
    float4 at0 = *(const float4*)(att + cl);
    float4 at1 = *(const float4*)(att + cl + 4);
    at4[0] = 0.4f*at0.x; at4[1] = 0.4f*at0.y; at4[2] = 0.4f*at0.z; at4[3] = 0.4f*at0.w;
    at4[4] = 0.4f*at1.x; at4[5] = 0.4f*at1.y; at4[6] = 0.4f*at1.z; at4[7] = 0.4f*at1.w;

    int e0 = row_ptr[node], e1 = row_ptr[node + 1];
    float acc[8] = {0.f,0.f,0.f,0.f,0.f,0.f,0.f,0.f};
    float suma = 0.f;
    for (int e = e0; e < e1; e += 8) {
        int ea = e + slot, eb = e + 4 + slot;
        bool va = ea < e1, vb = eb < e1;
        int sa = csr_src[va ? ea : e];
        int sb = csr_src[vb ? eb : e];
        bf16x8 xua = *(const bf16x8*)(xlr + (size_t)sa * 256 + cl);
        bf16x8 xub = *(const bf16x8*)(xlr + (size_t)sb * 256 + cl);
        float xa[8], xb[8];
        #pragma unroll
        for (int j = 0; j < 8; ++j) { xa[j] = bf2f((ushort_t)xua[j]); xb[j] = bf2f((ushort_t)xub[j]); }
        float pa = 0.f, qa = 0.f, pb = 0.f, qb = 0.f;
        #pragma unroll
        for (int j = 0; j < 8; ++j) {
            float sva = xa[j] + xr[j];
            float svb = xb[j] + xr[j];
            pa = fmaf(at4[j], fabsf(sva), pa);   // abs is a free VOP3 modifier
            qa = fmaf(at4[j], xa[j], qa);
            pb = fmaf(at4[j], fabsf(svb), pb);
            qb = fmaf(at4[j], xb[j], qb);
        }
        float ta = fmaf(1.5f, qa, pa);           // pa + 0.6/0.4 * qa
        float tb = fmaf(1.5f, qb, pb);
        ta += __shfl_xor(ta, 1); ta += __shfl_xor(ta, 2);
        tb += __shfl_xor(tb, 1); tb += __shfl_xor(tb, 2);
        float aa = va ? __expf(ta) : 0.f;
        float ab = vb ? __expf(tb) : 0.f;
        suma += aa + ab;
        #pragma unroll
        for (int j = 0; j < 8; ++j) acc[j] = fmaf(aa, xa[j], fmaf(ab, xb[j], acc[j]));
    }
    // combine the four edge slots
    suma += __shfl_xor(suma, 16); suma += __shfl_xor(suma, 32);
    #pragma unroll
    for (int j = 0; j < 8; ++j) {
        acc[j] += __shfl_xor(acc[j], 16);
        acc[j] += __shfl_xor(acc[j], 32);
    }
    if (slot == 0) {
        float inv = 1.0f / (suma + 1e-16f);
        float4 ob0 = *(const float4*)(b_out + cl);
        float4 ob1 = *(const float4*)(b_out + cl + 4);
        float ob[8] = {ob0.x, ob0.y, ob0.z, ob0.w, ob1.x, ob1.y, ob1.z, ob1.w};
        short r[8];
        #pragma unroll
        for (int j = 0; j < 8; ++j) r[j] = f2bf(fmaf(acc[j], inv, ob[j]));
        *(bf16x8*)(g + (size_t)node * 128 + cl) = *(const bf16x8*)r;
    }
}

// ---------------- PairNorm column sums (bf16 g) ----------------
__global__ void colsum_k(const ushort_t* __restrict__ g, float* __restrict__ colsum) {
    __shared__ float buf[256];
    int c = threadIdx.x & 127;
    int half = threadIdx.x >> 7;
    int r0 = blockIdx.x * 256;
    int rend = min(r0 + 256, NN);
    float s = 0.f;
    for (int r = r0 + half; r < rend; r += 2)
        s += bf2f(g[(size_t)r * 128 + c]);
    buf[threadIdx.x] = s;
    __syncthreads();
    if (threadIdx.x < 128)
        atomicAdd(&colsum[c], buf[threadIdx.x] + buf[threadIdx.x + 128]);
}

// ---------------- fused pairnorm + residual + layernorm (+relu) ----------------
__global__ __launch_bounds__(256, 4)
void finalize_k(const ushort_t* __restrict__ g, const float* __restrict__ colsum,
                const ushort_t* __restrict__ ident, const float* __restrict__ lng,
                const float* __restrict__ lnb, ushort_t* __restrict__ hout_bf,
                float* __restrict__ hout_f32, int is_final)
{
    int node = blockIdx.x * 4 + (threadIdx.x >> 6);
    int lane = threadIdx.x & 63;
    int j0 = lane * 2;
    const float invN = 1.0f / (float)NN;
    const float sqrtN = sqrtf((float)NN);

    ushort2 vu = *(const ushort2*)(g + (size_t)node * 128 + j0);
    float x0 = bf2f(vu.x) - colsum[j0] * invN;
    float x1 = bf2f(vu.y) - colsum[j0 + 1] * invN;
    float ss = x0 * x0 + x1 * x1;
    ss += __shfl_xor(ss, 1);  ss += __shfl_xor(ss, 2);  ss += __shfl_xor(ss, 4);
    ss += __shfl_xor(ss, 8);  ss += __shfl_xor(ss, 16); ss += __shfl_xor(ss, 32);
    float sc = sqrtN / (sqrtf(ss) + 1e-6f);

    ushort2 idu = *(const ushort2*)(ident + (size_t)node * 128 + j0);
    float t0 = x0 * sc + bf2f(idu.x);
    float t1 = x1 * sc + bf2f(idu.y);

    float m = t0 + t1;
    m += __shfl_xor(m, 1);  m += __shfl_xor(m, 2);  m += __shfl_xor(m, 4);
    m += __shfl_xor(m, 8);  m += __shfl_xor(m, 16); m += __shfl_xor(m, 32);
    m *= (1.0f / 128.0f);
    float d0 = t0 - m, d1 = t1 - m;
    float vv = d0 * d0 + d1 * d1;
    vv += __shfl_xor(vv, 1);  vv += __shfl_xor(vv, 2);  vv += __shfl_xor(vv, 4);
    vv += __shfl_xor(vv, 8);  vv += __shfl_xor(vv, 16); vv += __shfl_xor(vv, 32);
    vv *= (1.0f / 128.0f);
    float r = rsqrtf(vv + 1e-5f);

    float y0 = d0 * r * lng[j0]     + lnb[j0];
    float y1 = d1 * r * lng[j0 + 1] + lnb[j0 + 1];
    if (is_final) {
        float2 o; o.x = y0; o.y = y1;
        *(float2*)(hout_f32 + (size_t)node * 128 + j0) = o;
    } else {
        y0 = fmaxf(y0, 0.f); y1 = fmaxf(y1, 0.f);
        ushort2 o; o.x = (ushort_t)f2bf(y0); o.y = (ushort_t)f2bf(y1);
        *(ushort2*)(hout_bf + (size_t)node * 128 + j0) = o;
    }
}

// ---------------- host launch ----------------
extern "C" void kernel_launch(void* const* d_in, const int* in_sizes, int n_in,
                              void* d_out, int out_size, void* d_ws, size_t ws_size,
                              hipStream_t stream) {
    const float* x     = (const float*)d_in[0];
    const int*   ei    = (const int*)  d_in[1];   // [2][E]
    const float* w_in  = (const float*)d_in[2];
    const float* b_in  = (const float*)d_in[3];
    const float* Wl    = (const float*)d_in[4];
    const float* bl    = (const float*)d_in[5];
    const float* Wr    = (const float*)d_in[6];
    const float* att   = (const float*)d_in[7];
    const float* b_out = (const float*)d_in[8];
    const float* Wres  = (const float*)d_in[9];
    const float* bres  = (const float*)d_in[10];
    const float* ln_g  = (const float*)d_in[11];
    const float* ln_b  = (const float*)d_in[12];

    // workspace layout (bf16 feature buffers)
    ushort_t* h     = (ushort_t*)d_ws;                 // N*128 bf16
    ushort_t* xlr   = h + (size_t)NN * 128;            // N*256 bf16
    ushort_t* ident = xlr + (size_t)NN * 256;          // N*128 bf16
    ushort_t* g     = ident + (size_t)NN * 128;        // N*128 bf16
    ushort_t* wt    = g + (size_t)NN * 128;            // 9*128*128 bf16 (transposed weights)
    int*   row_ptr = (int*)(wt + 9 * 16384);           // N+1
    int*   cursor  = row_ptr + (NN + 1);               // N     (zeroed; also deg)
    float* colsum  = (float*)(cursor + NN);            // 3*128 (zeroed)
    int*   bsum    = (int*)(colsum + 384);             // 512
    int*   csr_src = bsum + 512;                       // E

    const int* e_src = ei;
    const int* e_dst = ei + NE;

    hipMemsetAsync(cursor, 0, (size_t)(NN + 384) * 4, stream);

    // weight transpose prep (once per call)
    prep_w_k<<<dim3(4, 4, 9), dim3(32, 8), 0, stream>>>(w_in, Wl, Wr, Wres, wt);

    // CSR build
    const int nb = (NN + 255) / 256;             // 391
    count_k  <<<NE / 256, 256, 0, stream>>>(e_dst, cursor);
    scan1_k  <<<nb, 256, 0, stream>>>(cursor, row_ptr, bsum);
    scan2_k  <<<1, 512, 0, stream>>>(bsum, nb, row_ptr + NN);
    scan3_k  <<<nb, 256, 0, stream>>>(row_ptr, bsum, cursor);
    scatter_k<<<NE / 256, 256, 0, stream>>>(e_src, e_dst, cursor, csr_src);

    const int gx = (NN + 127) / 128;             // 782

    // h = bf16(x @ w_in + b_in)
    gemm_k<1><<<dim3(gx, 1), 256, 0, stream>>>(x, wt, 0, 0, 0,
                                               b_in, nullptr, h, 128, nullptr, NN);

    for (int i = 0; i < 3; ++i) {
        // xlr = bf16(h @ [Wl | Wr] + [bl | 0]); (i>0) ident = bf16(h @ Wres + bres)
        gemm_k<0><<<dim3(gx, (i > 0) ? 3 : 2), 256, 0, stream>>>(
            h, wt, 1 + i, 4 + i, 7 + (i - 1),
            bl + i * 128, (i > 0) ? (bres + (i - 1) * 128) : nullptr,
            xlr, 256, ident, NN);
        gat_aggregate_k<<<NN / 4, 256, 0, stream>>>(xlr, row_ptr, csr_src,
                                                    att + i * 128, b_out + i * 128, g);
        colsum_k<<<nb, 256, 0, stream>>>(g, colsum + i * 128);
        finalize_k<<<NN / 4, 256, 0, stream>>>(g, colsum + i * 128,
                                               (i == 0) ? h : ident,
                                               ln_g + i * 128, ln_b + i * 128,
                                               h, (float*)d_out, (i == 2) ? 1 : 0);
    }
}